// Round 6
// baseline (446.360 us; speedup 1.0000x reference)
//
#include <hip/hip_runtime.h>
#include <stdint.h>

#define BB 32
#define LL 1024
#define CC 512
#define NN (BB * LL)      // 32768 positions
#define NLEVS 4
#define OUTD 11
#define LPAD 8            // zero pad rows per sequence (>= max dilation)
#define LROWS (LL + LPAD) // 1032 padded rows per sequence

typedef __attribute__((ext_vector_type(8))) short bf16x8;
typedef __attribute__((ext_vector_type(16))) float f32x16;

static __device__ __forceinline__ unsigned short f2bf(float f) {
    union { float f; uint32_t u; } v; v.f = f;
    uint32_t u = v.u;
    uint32_t r = (u + 0x7fffu + ((u >> 16) & 1u)) >> 16;  // RNE
    return (unsigned short)r;
}
static __device__ __forceinline__ float bf2f(unsigned short h) {
    union { uint32_t u; float f; } v; v.u = ((uint32_t)h) << 16;
    return v.f;
}

// async 16B global -> LDS (wave-uniform LDS base + lane*16)
static __device__ __forceinline__ void llds16(const unsigned short* g, unsigned short* l) {
    __builtin_amdgcn_global_load_lds(
        (const __attribute__((address_space(1))) unsigned int*)g,
        (__attribute__((address_space(3))) unsigned int*)l, 16, 0, 0);
}

// zero the LPAD pad rows of both bf16 activation buffers
__global__ __launch_bounds__(256) void zero_pad_kernel(
    unsigned short* __restrict__ Hb0, unsigned short* __restrict__ Hb1)
{
    int t = blockIdx.x * 256 + threadIdx.x;        // 32768 uint4 stores
    unsigned short* base = (t >> 14) ? Hb1 : Hb0;
    int rem = t & 16383;
    int p = rem >> 9;                               // sequence 0..31
    int q = rem & 511;                              // 512 uint4 per pad region
    size_t off = (size_t)p * (LROWS * CC) + (size_t)q * 8;
    *(uint4*)(base + off) = (uint4){0u, 0u, 0u, 0u};
}

// h0 bf16 padded: Hb0[prow][c] = bf16(emb[x[n]][c])
__global__ __launch_bounds__(256) void embed_kernel(
    const int* __restrict__ x, const float* __restrict__ emb,
    unsigned short* __restrict__ Hb0)
{
    int t = blockIdx.x * 256 + threadIdx.x;   // 8 halves each (64 chunks/row)
    int n = t >> 6;
    int c8 = (t & 63) * 8;
    int idx = x[n];
    const float* src = emb + (size_t)idx * CC + c8;
    float4 v0 = *(const float4*)src;
    float4 v1 = *(const float4*)(src + 4);
    ushort4 a, b;
    a.x = f2bf(v0.x); a.y = f2bf(v0.y); a.z = f2bf(v0.z); a.w = f2bf(v0.w);
    b.x = f2bf(v1.x); b.y = f2bf(v1.y); b.z = f2bf(v1.z); b.w = f2bf(v1.w);
    int prow = (n >> 10) * LROWS + LPAD + (n & (LL - 1));
    unsigned short* dst = Hb0 + (size_t)prow * CC + c8;
    *(ushort4*)dst = a;
    *(ushort4*)(dst + 4) = b;
}

// WpT[cv][j][co][h]: k-chunk-major packed weights for direct B-fragment loads.
// kidx = j*8+h; kidx<512 -> tap "current" (k=1, ci=kidx); kidx>=512 -> k=0, ci=kidx-512.
__global__ __launch_bounds__(256) void pack_w_kernel(
    const float* __restrict__ w1, const float* __restrict__ w2, unsigned short* __restrict__ WpT)
{
    int e = blockIdx.x * 256 + threadIdx.x;    // 8 * 524288 elements
    int cv = e >> 19;                           // conv 0..7 (lvl*2+conv)
    int r = e & 524287;
    int j = r >> 12;                            // 0..127
    int co = (r >> 3) & 511;
    int h = r & 7;
    int kidx = j * 8 + h;
    int k = (kidx < 512) ? 1 : 0;
    int ci = kidx & 511;
    int lvl = cv >> 1;
    const float* w = (cv & 1) ? w2 : w1;
    float val = w[(((size_t)(lvl * 512 + co) * 512) + ci) * 2 + k];
    WpT[e] = f2bf(val);
}

// GEMM: out[n][co] = act( A-window . W + bias ), all activations bf16.
// 128n x 128co tile, BK=128 ci-block (4 barrier-pairs), 32x32x16 MFMA (2x2/wave),
// dual-tap shared-A (136-row LDS window), B direct from global (k-major WpT).
// XCD swizzle: 4 co-blocks of an n-window land on one XCD -> L2 fetches A once.
// HAS_RES: v = relu(relu(acc+b) + res_bf16); in-place-safe (lane-owned elems).
template <bool HAS_RES>
__global__ __launch_bounds__(256, 4) void conv_gemm(
    const unsigned short* __restrict__ Ain, const unsigned short* __restrict__ WpT,
    const float* __restrict__ bias, const unsigned short* __restrict__ resB,
    unsigned short* __restrict__ OutB, int d)
{
    __shared__ unsigned short sA[136 * 128];  // rows rbase-8..rbase+127, 128 ci halves

    const int tid = threadIdx.x;
    const int wave = tid >> 6, lane = tid & 63;

    const int bid = blockIdx.x;               // 0..1023
    const int xcd = bid & 7;
    const int local = bid >> 3;               // 0..127
    const int cb = local >> 5;                // 0..3
    const int nb = xcd + 8 * (local & 31);    // 0..255
    const int co0 = cb * 128;
    const int n0 = nb * 128;

    const int rbase = (n0 >> 10) * LROWS + LPAD + (n0 & (LL - 1));
    const int wm = (wave >> 1) * 64;           // wave n-stripe
    const int wn = (wave & 1) * 64;            // wave co-stripe
    const int l31 = lane & 31;                 // MFMA row/col within 32
    const int g = lane >> 5;                   // k-group (0/1)

    // staging lane decomposition: 4 rows x 16 chunks of 16B per llds16
    const int r4 = lane >> 4;                  // row within 4-row call
    const int c16 = lane & 15;                 // LDS chunk position

    f32x16 acc[2][2];
#pragma unroll
    for (int i = 0; i < 2; ++i)
#pragma unroll
        for (int j = 0; j < 2; ++j)
#pragma unroll
            for (int e = 0; e < 16; ++e) acc[i][j][e] = 0.f;

    for (int it = 0; it < 4; ++it) {
        const int ci0 = it * 128;

        // stage A: 34 calls x (4 rows x 256B); global chunk = swizzle(position)
        for (int sg = wave; sg < 34; sg += 4) {
            int rho = (4 * (sg & 1) + r4) & 7;                 // row&7 of this lane's row
            int cg = (c16 & 8) | ((c16 & 7) ^ rho);            // global 16B chunk
            const unsigned short* gA =
                Ain + (size_t)(rbase - 8 + 4 * sg + r4) * CC + ci0 + cg * 8;
            llds16(gA, sA + (4 * sg) * 128);                   // lane*16B appended by HW
        }
        __syncthreads();

#pragma unroll
        for (int t = 0; t < 2; ++t) {
            const int shift = t ? d : 0;               // t=0: current tap; t=1: past tap
            const int rowoff = 8 - shift + wm;
            const int key = ((lane & 7) + 8 - shift) & 7;   // LDS low3 XOR key
#pragma unroll
            for (int kk = 0; kk < 8; ++kk) {
                const int c = 2 * kk + g;                       // chunk within it (0..15)
                const int cpos = (c & 8) | ((c & 7) ^ key);     // LDS position
                const int jb = t * 64 + it * 16 + c;            // global k-chunk
                bf16x8 af[2], bfr[2];
#pragma unroll
                for (int mt = 0; mt < 2; ++mt) {
                    int row = rowoff + mt * 32 + l31;
                    af[mt] = *(const bf16x8*)&sA[row * 128 + cpos * 8];
                }
                const unsigned short* bbase = WpT + ((size_t)jb * 512 + co0 + wn + l31) * 8;
#pragma unroll
                for (int nt = 0; nt < 2; ++nt)
                    bfr[nt] = *(const bf16x8*)(bbase + (size_t)nt * 32 * 8);
#pragma unroll
                for (int mt = 0; mt < 2; ++mt)
#pragma unroll
                    for (int nt = 0; nt < 2; ++nt)
                        acc[mt][nt] = __builtin_amdgcn_mfma_f32_32x32x16_bf16(
                            af[mt], bfr[nt], acc[mt][nt], 0, 0, 0);
            }
        }
        __syncthreads();
    }

    // epilogue: C/D 32x32 layout col=lane&31, row=(reg&3)+8*(reg>>2)+4*(lane>>5)
    float bv[2];
#pragma unroll
    for (int nt = 0; nt < 2; ++nt) bv[nt] = bias[co0 + wn + nt * 32 + l31];

#pragma unroll
    for (int mt = 0; mt < 2; ++mt) {
#pragma unroll
        for (int nt = 0; nt < 2; ++nt) {
            int co = co0 + wn + nt * 32 + l31;
#pragma unroll
            for (int reg = 0; reg < 16; ++reg) {
                int rowIn = (reg & 3) + 8 * (reg >> 2) + 4 * g;
                int prow = rbase + wm + mt * 32 + rowIn;
                size_t off = (size_t)prow * CC + co;
                float v = acc[mt][nt][reg] + bv[nt];
                v = fmaxf(v, 0.f);
                if (HAS_RES) {
                    v += bf2f(resB[off]);
                    v = fmaxf(v, 0.f);
                }
                OutB[off] = f2bf(v);
            }
        }
    }
}

// y[n][o] = mask[n] * (sum_c h[n][c]*dw[o][c] + db[o]);  one wave per n (bf16 h)
__global__ __launch_bounds__(256) void decode_kernel(
    const unsigned short* __restrict__ H, const float* __restrict__ dw,
    const float* __restrict__ db, const int* __restrict__ mask,
    float* __restrict__ out)
{
    __shared__ float sw[OUTD * CC];
    for (int i = threadIdx.x; i < OUTD * CC; i += 256) sw[i] = dw[i];
    __syncthreads();

    int wave = threadIdx.x >> 6, lane = threadIdx.x & 63;
    int n = blockIdx.x * 4 + wave;
    int prow = (n >> 10) * LROWS + LPAD + (n & (LL - 1));

    float hv[8];
#pragma unroll
    for (int j = 0; j < 8; ++j) hv[j] = bf2f(H[(size_t)prow * CC + lane + j * 64]);

    float accv[OUTD];
#pragma unroll
    for (int o = 0; o < OUTD; ++o) {
        float s = 0.f;
#pragma unroll
        for (int j = 0; j < 8; ++j) s += hv[j] * sw[o * CC + lane + j * 64];
        accv[o] = s;
    }
    float myv = 0.f;
#pragma unroll
    for (int o = 0; o < OUTD; ++o) {
        float s = accv[o];
#pragma unroll
        for (int m = 32; m; m >>= 1) s += __shfl_xor(s, m, 64);
        if (lane == o) myv = s;
    }
    if (lane < OUTD) {
        float mk = (mask[n] != 0) ? 1.f : 0.f;
        out[(size_t)n * OUTD + lane] = (myv + db[lane]) * mk;
    }
}

extern "C" void kernel_launch(void* const* d_in, const int* in_sizes, int n_in,
                              void* d_out, int out_size, void* d_ws, size_t ws_size,
                              hipStream_t stream)
{
    const int* x = (const int*)d_in[0];
    const int* mask = (const int*)d_in[1];   // jnp bool_ staged as int32
    const float* emb = (const float*)d_in[2];
    const float* w1 = (const float*)d_in[3];
    const float* b1 = (const float*)d_in[4];
    const float* w2 = (const float*)d_in[5];
    const float* b2 = (const float*)d_in[6];
    const float* dw = (const float*)d_in[7];
    const float* db = (const float*)d_in[8];
    float* out = (float*)d_out;

    char* ws = (char*)d_ws;
    const size_t HBB = (size_t)BB * LROWS * CC * 2;       // 33.8 MB (padded bf16)
    unsigned short* Hb0 = (unsigned short*)ws;
    unsigned short* Hb1 = (unsigned short*)(ws + HBB);
    unsigned short* WpT = (unsigned short*)(ws + 2 * HBB); // k-major bf16 weights, 8 MB

    zero_pad_kernel<<<128, 256, 0, stream>>>(Hb0, Hb1);
    embed_kernel<<<(NN * 64) / 256, 256, 0, stream>>>(x, emb, Hb0);
    pack_w_kernel<<<(NLEVS * 2 * CC * 1024) / 256, 256, 0, stream>>>(w1, w2, WpT);

    const int grid = (CC / 128) * (NN / 128);   // 4 * 256 = 1024 blocks = 4/CU
    for (int i = 0; i < NLEVS; ++i) {
        int d = 1 << i;
        const unsigned short* W1 = WpT + (size_t)(i * 2 + 0) * CC * 1024;
        const unsigned short* W2 = WpT + (size_t)(i * 2 + 1) * CC * 1024;
        // conv1: A=Hb0 -> Hb1
        conv_gemm<false><<<grid, 256, 0, stream>>>(Hb0, W1, b1 + i * CC, nullptr, Hb1, d);
        // conv2: A=Hb1, res=Hb0 (bf16), out=Hb0 (in place, lane-owned)
        conv_gemm<true><<<grid, 256, 0, stream>>>(Hb1, W2, b2 + i * CC, Hb0, Hb0, d);
    }
    decode_kernel<<<NN / 4, 256, 0, stream>>>(Hb0, dw, db, mask, out);
}

// Round 7
// 419.684 us; speedup vs baseline: 1.0636x; 1.0636x over previous
//
#include <hip/hip_runtime.h>
#include <stdint.h>

#define BB 32
#define LL 1024
#define CC 512
#define NN (BB * LL)      // 32768 positions
#define NLEVS 4
#define OUTD 11
#define LPAD 8            // zero pad rows per sequence (>= max dilation)
#define LROWS (LL + LPAD) // 1032 padded rows per sequence

typedef __attribute__((ext_vector_type(8))) short bf16x8;
typedef __attribute__((ext_vector_type(4))) float f32x4;

static __device__ __forceinline__ unsigned short f2bf(float f) {
    union { float f; uint32_t u; } v; v.f = f;
    uint32_t u = v.u;
    uint32_t r = (u + 0x7fffu + ((u >> 16) & 1u)) >> 16;  // RNE
    return (unsigned short)r;
}
static __device__ __forceinline__ float bf2f(unsigned short h) {
    union { uint32_t u; float f; } v; v.u = ((uint32_t)h) << 16;
    return v.f;
}

// async 16B global -> LDS (wave-uniform LDS base + lane*16)
static __device__ __forceinline__ void llds16(const unsigned short* g, unsigned short* l) {
    __builtin_amdgcn_global_load_lds(
        (const __attribute__((address_space(1))) unsigned int*)g,
        (__attribute__((address_space(3))) unsigned int*)l, 16, 0, 0);
}

// zero the LPAD pad rows of both bf16 activation buffers
__global__ __launch_bounds__(256) void zero_pad_kernel(
    unsigned short* __restrict__ Hb0, unsigned short* __restrict__ Hb1)
{
    int t = blockIdx.x * 256 + threadIdx.x;        // 32768 uint4 stores
    unsigned short* base = (t >> 14) ? Hb1 : Hb0;
    int rem = t & 16383;
    int p = rem >> 9;                               // sequence 0..31
    int q = rem & 511;                              // 512 uint4 per pad region
    size_t off = (size_t)p * (LROWS * CC) + (size_t)q * 8;
    *(uint4*)(base + off) = (uint4){0u, 0u, 0u, 0u};
}

// h0 bf16 padded: Hb0[prow][c] = bf16(emb[x[n]][c])
__global__ __launch_bounds__(256) void embed_kernel(
    const int* __restrict__ x, const float* __restrict__ emb,
    unsigned short* __restrict__ Hb0)
{
    int t = blockIdx.x * 256 + threadIdx.x;   // 8 halves each (64 chunks/row)
    int n = t >> 6;
    int c8 = (t & 63) * 8;
    int idx = x[n];
    const float* src = emb + (size_t)idx * CC + c8;
    float4 v0 = *(const float4*)src;
    float4 v1 = *(const float4*)(src + 4);
    ushort4 a, b;
    a.x = f2bf(v0.x); a.y = f2bf(v0.y); a.z = f2bf(v0.z); a.w = f2bf(v0.w);
    b.x = f2bf(v1.x); b.y = f2bf(v1.y); b.z = f2bf(v1.z); b.w = f2bf(v1.w);
    int prow = (n >> 10) * LROWS + LPAD + (n & (LL - 1));
    unsigned short* dst = Hb0 + (size_t)prow * CC + c8;
    *(ushort4*)dst = a;
    *(ushort4*)(dst + 4) = b;
}

// WpT[cv][j][co][h]: k-chunk-major packed weights for direct B-fragment loads.
// kidx = j*8+h; kidx<512 -> tap "current" (k=1, ci=kidx); kidx>=512 -> k=0, ci=kidx-512.
__global__ __launch_bounds__(256) void pack_w_kernel(
    const float* __restrict__ w1, const float* __restrict__ w2, unsigned short* __restrict__ WpT)
{
    int e = blockIdx.x * 256 + threadIdx.x;    // 8 * 524288 elements
    int cv = e >> 19;                           // conv 0..7 (lvl*2+conv)
    int r = e & 524287;
    int j = r >> 12;                            // 0..127
    int co = (r >> 3) & 511;
    int h = r & 7;
    int kidx = j * 8 + h;
    int k = (kidx < 512) ? 1 : 0;
    int ci = kidx & 511;
    int lvl = cv >> 1;
    const float* w = (cv & 1) ? w2 : w1;
    float val = w[(((size_t)(lvl * 512 + co) * 512) + ci) * 2 + k];
    WpT[e] = f2bf(val);
}

// GEMM: out[n][co] = act( A-window . W + bias ), all activations bf16.
// 128n x 128co tile, BK=128 ci-block (4 staging phases), 16x16x32 MFMA 4x4/wave
// (16-row lane spread = conflict-free bank geometry), dual-tap shared-A
// (136-row LDS window), B direct from global (k-major WpT).
// 1-step software pipeline: prefetch next step's A/B frags before current MFMAs.
// XCD swizzle: 4 co-blocks of an n-window land on one XCD -> L2 fetches A once.
// HAS_RES: v = relu(relu(acc+b) + res_bf16); in-place-safe (lane-owned elems).
template <bool HAS_RES>
__global__ __launch_bounds__(256, 3) void conv_gemm(
    const unsigned short* __restrict__ Ain, const unsigned short* __restrict__ WpT,
    const float* __restrict__ bias, const unsigned short* __restrict__ resB,
    unsigned short* __restrict__ OutB, int d)
{
    __shared__ unsigned short sA[136 * 128];  // rows rbase-8..rbase+127, 128 ci halves

    const int tid = threadIdx.x;
    const int wave = tid >> 6, lane = tid & 63;

    const int bid = blockIdx.x;               // 0..1023
    const int xcd = bid & 7;
    const int local = bid >> 3;               // 0..127
    const int cb = local >> 5;                // 0..3
    const int nb = xcd + 8 * (local & 31);    // 0..255
    const int co0 = cb * 128;
    const int n0 = nb * 128;

    const int rbase = (n0 >> 10) * LROWS + LPAD + (n0 & (LL - 1));
    const int wm = (wave >> 1) * 64;           // wave n-stripe
    const int wn = (wave & 1) * 64;            // wave co-stripe
    const int lm = lane & 15, quad = lane >> 4;

    // staging lane decomposition: 4 rows x 16 chunks of 16B per llds16
    const int r4 = lane >> 4;                  // row within 4-row call
    const int c16 = lane & 15;                 // LDS chunk position

    f32x4 acc[4][4];
#pragma unroll
    for (int i = 0; i < 4; ++i)
#pragma unroll
        for (int j = 0; j < 4; ++j) acc[i][j] = (f32x4){0.f, 0.f, 0.f, 0.f};

    for (int it = 0; it < 4; ++it) {
        const int ci0 = it * 128;

        // stage A: 34 calls x (4 rows x 256B); global chunk = 3-bit swizzle(position)
        for (int sg = wave; sg < 34; sg += 4) {
            int rho = (4 * sg + r4) & 7;                       // row&7 of lane's row
            int cg = (c16 & 8) | ((c16 & 7) ^ rho);            // global 16B chunk
            const unsigned short* gA =
                Ain + (size_t)(rbase - 8 + 4 * sg + r4) * CC + ci0 + cg * 8;
            llds16(gA, sA + (4 * sg) * 128);                   // lane*16B appended by HW
        }
        __syncthreads();

        // step s = t*4 + ks: t = tap (0 current, 1 past), ks = K=32 slice
        auto loadA = [&](int s, bf16x8* af) {
            const int t = s >> 2, ks = s & 3;
            const int shift = t ? d : 0;
            const int rowoff = 8 - shift + wm;
            const int key = (8 - shift + lm) & 7;              // row&7 of read row
            const int c = ks * 4 + quad;                       // 16B chunk 0..15
            const int cpos = (c & 8) | ((c & 7) ^ key);
#pragma unroll
            for (int mt = 0; mt < 4; ++mt)
                af[mt] = *(const bf16x8*)&sA[(rowoff + mt * 16 + lm) * 128 + cpos * 8];
        };
        auto loadB = [&](int s, bf16x8* bf) {
            const int t = s >> 2, ks = s & 3;
            const int jb = t * 64 + it * 16 + ks * 4 + quad;   // global k-chunk
            const unsigned short* bbase = WpT + ((size_t)jb * 512 + co0 + wn + lm) * 8;
#pragma unroll
            for (int nt = 0; nt < 4; ++nt)
                bf[nt] = *(const bf16x8*)(bbase + (size_t)nt * 16 * 8);
        };

        bf16x8 afc[4], bfc[4], afn[4], bfn[4];
        loadA(0, afc);
        loadB(0, bfc);
#pragma unroll
        for (int s = 0; s < 8; ++s) {
            if (s < 7) { loadA(s + 1, afn); loadB(s + 1, bfn); }
#pragma unroll
            for (int mt = 0; mt < 4; ++mt)
#pragma unroll
                for (int nt = 0; nt < 4; ++nt)
                    acc[mt][nt] = __builtin_amdgcn_mfma_f32_16x16x32_bf16(
                        afc[mt], bfc[nt], acc[mt][nt], 0, 0, 0);
            if (s < 7) {
#pragma unroll
                for (int q2 = 0; q2 < 4; ++q2) { afc[q2] = afn[q2]; bfc[q2] = bfn[q2]; }
            }
        }
        __syncthreads();
    }

    // epilogue: C/D layout col(co)=lane&15, row(n)=quad*4+reg
    float bv[4];
#pragma unroll
    for (int nt = 0; nt < 4; ++nt) bv[nt] = bias[co0 + wn + nt * 16 + lm];

#pragma unroll
    for (int mt = 0; mt < 4; ++mt) {
        int prow0 = rbase + wm + mt * 16 + quad * 4;
#pragma unroll
        for (int nt = 0; nt < 4; ++nt) {
            int co = co0 + wn + nt * 16 + lm;
#pragma unroll
            for (int r = 0; r < 4; ++r) {
                size_t off = (size_t)(prow0 + r) * CC + co;
                float v = acc[mt][nt][r] + bv[nt];
                v = fmaxf(v, 0.f);
                if (HAS_RES) {
                    v += bf2f(resB[off]);
                    v = fmaxf(v, 0.f);
                }
                OutB[off] = f2bf(v);
            }
        }
    }
}

// y[n][o] = mask[n] * (sum_c h[n][c]*dw[o][c] + db[o]);  one wave per n (bf16 h)
__global__ __launch_bounds__(256) void decode_kernel(
    const unsigned short* __restrict__ H, const float* __restrict__ dw,
    const float* __restrict__ db, const int* __restrict__ mask,
    float* __restrict__ out)
{
    __shared__ float sw[OUTD * CC];
    for (int i = threadIdx.x; i < OUTD * CC; i += 256) sw[i] = dw[i];
    __syncthreads();

    int wave = threadIdx.x >> 6, lane = threadIdx.x & 63;
    int n = blockIdx.x * 4 + wave;
    int prow = (n >> 10) * LROWS + LPAD + (n & (LL - 1));

    float hv[8];
#pragma unroll
    for (int j = 0; j < 8; ++j) hv[j] = bf2f(H[(size_t)prow * CC + lane + j * 64]);

    float accv[OUTD];
#pragma unroll
    for (int o = 0; o < OUTD; ++o) {
        float s = 0.f;
#pragma unroll
        for (int j = 0; j < 8; ++j) s += hv[j] * sw[o * CC + lane + j * 64];
        accv[o] = s;
    }
    float myv = 0.f;
#pragma unroll
    for (int o = 0; o < OUTD; ++o) {
        float s = accv[o];
#pragma unroll
        for (int m = 32; m; m >>= 1) s += __shfl_xor(s, m, 64);
        if (lane == o) myv = s;
    }
    if (lane < OUTD) {
        float mk = (mask[n] != 0) ? 1.f : 0.f;
        out[(size_t)n * OUTD + lane] = (myv + db[lane]) * mk;
    }
}

extern "C" void kernel_launch(void* const* d_in, const int* in_sizes, int n_in,
                              void* d_out, int out_size, void* d_ws, size_t ws_size,
                              hipStream_t stream)
{
    const int* x = (const int*)d_in[0];
    const int* mask = (const int*)d_in[1];   // jnp bool_ staged as int32
    const float* emb = (const float*)d_in[2];
    const float* w1 = (const float*)d_in[3];
    const float* b1 = (const float*)d_in[4];
    const float* w2 = (const float*)d_in[5];
    const float* b2 = (const float*)d_in[6];
    const float* dw = (const float*)d_in[7];
    const float* db = (const float*)d_in[8];
    float* out = (float*)d_out;

    char* ws = (char*)d_ws;
    const size_t HBB = (size_t)BB * LROWS * CC * 2;       // 33.8 MB (padded bf16)
    unsigned short* Hb0 = (unsigned short*)ws;
    unsigned short* Hb1 = (unsigned short*)(ws + HBB);
    unsigned short* WpT = (unsigned short*)(ws + 2 * HBB); // k-major bf16 weights, 8 MB

    zero_pad_kernel<<<128, 256, 0, stream>>>(Hb0, Hb1);
    embed_kernel<<<(NN * 64) / 256, 256, 0, stream>>>(x, emb, Hb0);
    pack_w_kernel<<<(NLEVS * 2 * CC * 1024) / 256, 256, 0, stream>>>(w1, w2, WpT);

    const int grid = (CC / 128) * (NN / 128);   // 4 * 256 = 1024 blocks
    for (int i = 0; i < NLEVS; ++i) {
        int d = 1 << i;
        const unsigned short* W1 = WpT + (size_t)(i * 2 + 0) * CC * 1024;
        const unsigned short* W2 = WpT + (size_t)(i * 2 + 1) * CC * 1024;
        // conv1: A=Hb0 -> Hb1
        conv_gemm<false><<<grid, 256, 0, stream>>>(Hb0, W1, b1 + i * CC, nullptr, Hb1, d);
        // conv2: A=Hb1, res=Hb0 (bf16), out=Hb0 (in place, lane-owned)
        conv_gemm<true><<<grid, 256, 0, stream>>>(Hb1, W2, b2 + i * CC, Hb0, Hb0, d);
    }
    decode_kernel<<<NN / 4, 256, 0, stream>>>(Hb0, dw, db, mask, out);
}

// Round 8
// 403.917 us; speedup vs baseline: 1.1051x; 1.0390x over previous
//
#include <hip/hip_runtime.h>
#include <stdint.h>

#define BB 32
#define LL 1024
#define CC 512
#define NN (BB * LL)      // 32768 positions
#define NLEVS 4
#define OUTD 11
#define LPAD 8            // zero pad rows per sequence (>= max dilation)
#define LROWS (LL + LPAD) // 1032 padded rows per sequence

typedef __attribute__((ext_vector_type(8))) short bf16x8;
typedef __attribute__((ext_vector_type(4))) float f32x4;

static __device__ __forceinline__ unsigned short f2bf(float f) {
    union { float f; uint32_t u; } v; v.f = f;
    uint32_t u = v.u;
    uint32_t r = (u + 0x7fffu + ((u >> 16) & 1u)) >> 16;  // RNE
    return (unsigned short)r;
}
static __device__ __forceinline__ float bf2f(unsigned short h) {
    union { uint32_t u; float f; } v; v.u = ((uint32_t)h) << 16;
    return v.f;
}

// async 16B global -> LDS (wave-uniform LDS base + lane*16)
static __device__ __forceinline__ void llds16(const unsigned short* g, unsigned short* l) {
    __builtin_amdgcn_global_load_lds(
        (const __attribute__((address_space(1))) unsigned int*)g,
        (__attribute__((address_space(3))) unsigned int*)l, 16, 0, 0);
}

// zero the LPAD pad rows of both bf16 activation buffers
__global__ __launch_bounds__(256) void zero_pad_kernel(
    unsigned short* __restrict__ Hb0, unsigned short* __restrict__ Hb1)
{
    int t = blockIdx.x * 256 + threadIdx.x;        // 32768 uint4 stores
    unsigned short* base = (t >> 14) ? Hb1 : Hb0;
    int rem = t & 16383;
    int p = rem >> 9;                               // sequence 0..31
    int q = rem & 511;                              // 512 uint4 per pad region
    size_t off = (size_t)p * (LROWS * CC) + (size_t)q * 8;
    *(uint4*)(base + off) = (uint4){0u, 0u, 0u, 0u};
}

// h0 bf16 padded: Hb0[prow][c] = bf16(emb[x[n]][c])
__global__ __launch_bounds__(256) void embed_kernel(
    const int* __restrict__ x, const float* __restrict__ emb,
    unsigned short* __restrict__ Hb0)
{
    int t = blockIdx.x * 256 + threadIdx.x;   // 8 halves each (64 chunks/row)
    int n = t >> 6;
    int c8 = (t & 63) * 8;
    int idx = x[n];
    const float* src = emb + (size_t)idx * CC + c8;
    float4 v0 = *(const float4*)src;
    float4 v1 = *(const float4*)(src + 4);
    ushort4 a, b;
    a.x = f2bf(v0.x); a.y = f2bf(v0.y); a.z = f2bf(v0.z); a.w = f2bf(v0.w);
    b.x = f2bf(v1.x); b.y = f2bf(v1.y); b.z = f2bf(v1.z); b.w = f2bf(v1.w);
    int prow = (n >> 10) * LROWS + LPAD + (n & (LL - 1));
    unsigned short* dst = Hb0 + (size_t)prow * CC + c8;
    *(ushort4*)dst = a;
    *(ushort4*)(dst + 4) = b;
}

// WpT[cv][j][co][h]: k-chunk-major packed weights for direct B-fragment loads.
// kidx = j*8+h; kidx<512 -> tap "current" (k=1, ci=kidx); kidx>=512 -> k=0, ci=kidx-512.
__global__ __launch_bounds__(256) void pack_w_kernel(
    const float* __restrict__ w1, const float* __restrict__ w2, unsigned short* __restrict__ WpT)
{
    int e = blockIdx.x * 256 + threadIdx.x;    // 8 * 524288 elements
    int cv = e >> 19;                           // conv 0..7 (lvl*2+conv)
    int r = e & 524287;
    int j = r >> 12;                            // 0..127
    int co = (r >> 3) & 511;
    int h = r & 7;
    int kidx = j * 8 + h;
    int k = (kidx < 512) ? 1 : 0;
    int ci = kidx & 511;
    int lvl = cv >> 1;
    const float* w = (cv & 1) ? w2 : w1;
    float val = w[(((size_t)(lvl * 512 + co) * 512) + ci) * 2 + k];
    WpT[e] = f2bf(val);
}

// dwp[jb][o16][8]: decoder weights, k-chunk-major bf16, o padded 11->16 with zeros
__global__ __launch_bounds__(256) void pack_dw_kernel(
    const float* __restrict__ dw, unsigned short* __restrict__ dwp)
{
    int e = blockIdx.x * 256 + threadIdx.x;    // 64*16*8 = 8192 halves
    int jb = e >> 7;
    int o = (e >> 3) & 15;
    int j = e & 7;
    float val = (o < OUTD) ? dw[o * CC + jb * 8 + j] : 0.f;
    dwp[e] = f2bf(val);
}

// GEMM: out[n][co] = act( A-window . W + bias ), all activations bf16.
// 128n x 128co tile, BK=128 ci-block (4 staging phases), 16x16x32 MFMA 4x4/wave
// (16-row lane spread = conflict-free bank geometry), dual-tap shared-A
// (136-row LDS window), B direct from global (k-major WpT).
// 1-step software pipeline: prefetch next step's A/B frags before current MFMAs.
// XCD swizzle: 4 co-blocks of an n-window land on one XCD -> L2 fetches A once.
// HAS_RES: v = relu(relu(acc+b) + res_bf16); in-place-safe (lane-owned elems).
template <bool HAS_RES>
__global__ __launch_bounds__(256, 3) void conv_gemm(
    const unsigned short* __restrict__ Ain, const unsigned short* __restrict__ WpT,
    const float* __restrict__ bias, const unsigned short* __restrict__ resB,
    unsigned short* __restrict__ OutB, int d)
{
    __shared__ unsigned short sA[136 * 128];  // rows rbase-8..rbase+127, 128 ci halves

    const int tid = threadIdx.x;
    const int wave = tid >> 6, lane = tid & 63;

    const int bid = blockIdx.x;               // 0..1023
    const int xcd = bid & 7;
    const int local = bid >> 3;               // 0..127
    const int cb = local >> 5;                // 0..3
    const int nb = xcd + 8 * (local & 31);    // 0..255
    const int co0 = cb * 128;
    const int n0 = nb * 128;

    const int rbase = (n0 >> 10) * LROWS + LPAD + (n0 & (LL - 1));
    const int wm = (wave >> 1) * 64;           // wave n-stripe
    const int wn = (wave & 1) * 64;            // wave co-stripe
    const int lm = lane & 15, quad = lane >> 4;

    // staging lane decomposition: 4 rows x 16 chunks of 16B per llds16
    const int r4 = lane >> 4;                  // row within 4-row call
    const int c16 = lane & 15;                 // LDS chunk position

    f32x4 acc[4][4];
#pragma unroll
    for (int i = 0; i < 4; ++i)
#pragma unroll
        for (int j = 0; j < 4; ++j) acc[i][j] = (f32x4){0.f, 0.f, 0.f, 0.f};

    for (int it = 0; it < 4; ++it) {
        const int ci0 = it * 128;

        // stage A: 34 calls x (4 rows x 256B); global chunk = 3-bit swizzle(position)
        for (int sg = wave; sg < 34; sg += 4) {
            int rho = (4 * sg + r4) & 7;                       // row&7 of lane's row
            int cg = (c16 & 8) | ((c16 & 7) ^ rho);            // global 16B chunk
            const unsigned short* gA =
                Ain + (size_t)(rbase - 8 + 4 * sg + r4) * CC + ci0 + cg * 8;
            llds16(gA, sA + (4 * sg) * 128);                   // lane*16B appended by HW
        }
        __syncthreads();

        // step s = t*4 + ks: t = tap (0 current, 1 past), ks = K=32 slice
        auto loadA = [&](int s, bf16x8* af) {
            const int t = s >> 2, ks = s & 3;
            const int shift = t ? d : 0;
            const int rowoff = 8 - shift + wm;
            const int key = (8 - shift + lm) & 7;              // row&7 of read row
            const int c = ks * 4 + quad;                       // 16B chunk 0..15
            const int cpos = (c & 8) | ((c & 7) ^ key);
#pragma unroll
            for (int mt = 0; mt < 4; ++mt)
                af[mt] = *(const bf16x8*)&sA[(rowoff + mt * 16 + lm) * 128 + cpos * 8];
        };
        auto loadB = [&](int s, bf16x8* bf) {
            const int t = s >> 2, ks = s & 3;
            const int jb = t * 64 + it * 16 + ks * 4 + quad;   // global k-chunk
            const unsigned short* bbase = WpT + ((size_t)jb * 512 + co0 + wn + lm) * 8;
#pragma unroll
            for (int nt = 0; nt < 4; ++nt)
                bf[nt] = *(const bf16x8*)(bbase + (size_t)nt * 16 * 8);
        };

        bf16x8 afc[4], bfc[4], afn[4], bfn[4];
        loadA(0, afc);
        loadB(0, bfc);
#pragma unroll
        for (int s = 0; s < 8; ++s) {
            if (s < 7) { loadA(s + 1, afn); loadB(s + 1, bfn); }
#pragma unroll
            for (int mt = 0; mt < 4; ++mt)
#pragma unroll
                for (int nt = 0; nt < 4; ++nt)
                    acc[mt][nt] = __builtin_amdgcn_mfma_f32_16x16x32_bf16(
                        afc[mt], bfc[nt], acc[mt][nt], 0, 0, 0);
            if (s < 7) {
#pragma unroll
                for (int q2 = 0; q2 < 4; ++q2) { afc[q2] = afn[q2]; bfc[q2] = bfn[q2]; }
            }
        }
        __syncthreads();
    }

    // epilogue: C/D layout col(co)=lane&15, row(n)=quad*4+reg
    float bv[4];
#pragma unroll
    for (int nt = 0; nt < 4; ++nt) bv[nt] = bias[co0 + wn + nt * 16 + lm];

#pragma unroll
    for (int mt = 0; mt < 4; ++mt) {
        int prow0 = rbase + wm + mt * 16 + quad * 4;
#pragma unroll
        for (int nt = 0; nt < 4; ++nt) {
            int co = co0 + wn + nt * 16 + lm;
#pragma unroll
            for (int r = 0; r < 4; ++r) {
                size_t off = (size_t)(prow0 + r) * CC + co;
                float v = acc[mt][nt][r] + bv[nt];
                v = fmaxf(v, 0.f);
                if (HAS_RES) {
                    v += bf2f(resB[off]);
                    v = fmaxf(v, 0.f);
                }
                OutB[off] = f2bf(v);
            }
        }
    }
}

// decode as per-wave MFMA mini-GEMM: M=16 n, N=16 o (11 real), K=512.
// A-frag: lane(lm,quad) holds H[n0+lm][ks*32+quad*8 .. +8]  (A[m=lane&15][k=quad*8+j])
// B-frag from dwp (k-chunk-major, 16 KB, L1-resident).
// C/D: col=o=lane&15, row(n within 16)=quad*4+reg.
__global__ __launch_bounds__(256) void decode_kernel(
    const unsigned short* __restrict__ H, const unsigned short* __restrict__ dwp,
    const float* __restrict__ db, const int* __restrict__ mask,
    float* __restrict__ out)
{
    const int wave = threadIdx.x >> 6, lane = threadIdx.x & 63;
    const int lm = lane & 15, quad = lane >> 4;
    const int n0 = blockIdx.x * 64 + wave * 16;    // 64-aligned: no seq crossing
    const int prow = ((n0 + lm) >> 10) * LROWS + LPAD + ((n0 + lm) & (LL - 1));

    f32x4 acc = (f32x4){0.f, 0.f, 0.f, 0.f};
#pragma unroll
    for (int ks = 0; ks < 16; ++ks) {
        bf16x8 af = *(const bf16x8*)&H[(size_t)prow * CC + ks * 32 + quad * 8];
        bf16x8 bf = *(const bf16x8*)&dwp[((size_t)(ks * 4 + quad) * 16 + lm) * 8];
        acc = __builtin_amdgcn_mfma_f32_16x16x32_bf16(af, bf, acc, 0, 0, 0);
    }

    if (lm < OUTD) {
        float bo = db[lm];
#pragma unroll
        for (int r = 0; r < 4; ++r) {
            int n = n0 + quad * 4 + r;
            float v = (mask[n] != 0) ? (acc[r] + bo) : 0.f;
            out[(size_t)n * OUTD + lm] = v;
        }
    }
}

extern "C" void kernel_launch(void* const* d_in, const int* in_sizes, int n_in,
                              void* d_out, int out_size, void* d_ws, size_t ws_size,
                              hipStream_t stream)
{
    const int* x = (const int*)d_in[0];
    const int* mask = (const int*)d_in[1];   // jnp bool_ staged as int32
    const float* emb = (const float*)d_in[2];
    const float* w1 = (const float*)d_in[3];
    const float* b1 = (const float*)d_in[4];
    const float* w2 = (const float*)d_in[5];
    const float* b2 = (const float*)d_in[6];
    const float* dw = (const float*)d_in[7];
    const float* db = (const float*)d_in[8];
    float* out = (float*)d_out;

    char* ws = (char*)d_ws;
    const size_t HBB = (size_t)BB * LROWS * CC * 2;       // 33.8 MB (padded bf16)
    unsigned short* Hb0 = (unsigned short*)ws;
    unsigned short* Hb1 = (unsigned short*)(ws + HBB);
    unsigned short* WpT = (unsigned short*)(ws + 2 * HBB); // k-major bf16 weights, 8 MB
    unsigned short* dwp = (unsigned short*)(ws + 2 * HBB + (size_t)NLEVS * 2 * CC * 1024 * 2);

    zero_pad_kernel<<<128, 256, 0, stream>>>(Hb0, Hb1);
    embed_kernel<<<(NN * 64) / 256, 256, 0, stream>>>(x, emb, Hb0);
    pack_w_kernel<<<(NLEVS * 2 * CC * 1024) / 256, 256, 0, stream>>>(w1, w2, WpT);
    pack_dw_kernel<<<32, 256, 0, stream>>>(dw, dwp);

    const int grid = (CC / 128) * (NN / 128);   // 4 * 256 = 1024 blocks
    for (int i = 0; i < NLEVS; ++i) {
        int d = 1 << i;
        const unsigned short* W1 = WpT + (size_t)(i * 2 + 0) * CC * 1024;
        const unsigned short* W2 = WpT + (size_t)(i * 2 + 1) * CC * 1024;
        // conv1: A=Hb0 -> Hb1
        conv_gemm<false><<<grid, 256, 0, stream>>>(Hb0, W1, b1 + i * CC, nullptr, Hb1, d);
        // conv2: A=Hb1, res=Hb0 (bf16), out=Hb0 (in place, lane-owned)
        conv_gemm<true><<<grid, 256, 0, stream>>>(Hb1, W2, b2 + i * CC, Hb0, Hb0, d);
    }
    decode_kernel<<<NN / 64, 256, 0, stream>>>(Hb0, dwp, db, mask, out);
}

// Round 9
// 395.807 us; speedup vs baseline: 1.1277x; 1.0205x over previous
//
#include <hip/hip_runtime.h>
#include <stdint.h>

#define BB 32
#define LL 1024
#define CC 512
#define NN (BB * LL)      // 32768 positions
#define NLEVS 4
#define OUTD 11
#define LPAD 8            // zero pad rows per sequence (>= max dilation)
#define LROWS (LL + LPAD) // 1032 padded rows per sequence

typedef __attribute__((ext_vector_type(8))) short bf16x8;
typedef __attribute__((ext_vector_type(4))) float f32x4;

static __device__ __forceinline__ unsigned short f2bf(float f) {
    union { float f; uint32_t u; } v; v.f = f;
    uint32_t u = v.u;
    uint32_t r = (u + 0x7fffu + ((u >> 16) & 1u)) >> 16;  // RNE
    return (unsigned short)r;
}
static __device__ __forceinline__ float bf2f(unsigned short h) {
    union { uint32_t u; float f; } v; v.u = ((uint32_t)h) << 16;
    return v.f;
}

// async 16B global -> LDS (wave-uniform LDS base + lane*16)
static __device__ __forceinline__ void llds16(const unsigned short* g, unsigned short* l) {
    __builtin_amdgcn_global_load_lds(
        (const __attribute__((address_space(1))) unsigned int*)g,
        (__attribute__((address_space(3))) unsigned int*)l, 16, 0, 0);
}

// zero the LPAD pad rows of both bf16 activation buffers
__global__ __launch_bounds__(256) void zero_pad_kernel(
    unsigned short* __restrict__ Hb0, unsigned short* __restrict__ Hb1)
{
    int t = blockIdx.x * 256 + threadIdx.x;        // 32768 uint4 stores
    unsigned short* base = (t >> 14) ? Hb1 : Hb0;
    int rem = t & 16383;
    int p = rem >> 9;                               // sequence 0..31
    int q = rem & 511;                              // 512 uint4 per pad region
    size_t off = (size_t)p * (LROWS * CC) + (size_t)q * 8;
    *(uint4*)(base + off) = (uint4){0u, 0u, 0u, 0u};
}

// h0 bf16 padded: Hb0[prow][c] = bf16(emb[x[n]][c])
__global__ __launch_bounds__(256) void embed_kernel(
    const int* __restrict__ x, const float* __restrict__ emb,
    unsigned short* __restrict__ Hb0)
{
    int t = blockIdx.x * 256 + threadIdx.x;   // 8 halves each (64 chunks/row)
    int n = t >> 6;
    int c8 = (t & 63) * 8;
    int idx = x[n];
    const float* src = emb + (size_t)idx * CC + c8;
    float4 v0 = *(const float4*)src;
    float4 v1 = *(const float4*)(src + 4);
    ushort4 a, b;
    a.x = f2bf(v0.x); a.y = f2bf(v0.y); a.z = f2bf(v0.z); a.w = f2bf(v0.w);
    b.x = f2bf(v1.x); b.y = f2bf(v1.y); b.z = f2bf(v1.z); b.w = f2bf(v1.w);
    int prow = (n >> 10) * LROWS + LPAD + (n & (LL - 1));
    unsigned short* dst = Hb0 + (size_t)prow * CC + c8;
    *(ushort4*)dst = a;
    *(ushort4*)(dst + 4) = b;
}

// WpT[cv][j][co][h]: k-chunk-major packed weights for direct B-fragment loads.
// kidx = j*8+h; kidx<512 -> tap "current" (k=1, ci=kidx); kidx>=512 -> k=0, ci=kidx-512.
__global__ __launch_bounds__(256) void pack_w_kernel(
    const float* __restrict__ w1, const float* __restrict__ w2, unsigned short* __restrict__ WpT)
{
    int e = blockIdx.x * 256 + threadIdx.x;    // 8 * 524288 elements
    int cv = e >> 19;                           // conv 0..7 (lvl*2+conv)
    int r = e & 524287;
    int j = r >> 12;                            // 0..127
    int co = (r >> 3) & 511;
    int h = r & 7;
    int kidx = j * 8 + h;
    int k = (kidx < 512) ? 1 : 0;
    int ci = kidx & 511;
    int lvl = cv >> 1;
    const float* w = (cv & 1) ? w2 : w1;
    float val = w[(((size_t)(lvl * 512 + co) * 512) + ci) * 2 + k];
    WpT[e] = f2bf(val);
}

// dwp[jb][o16][8]: decoder weights, k-chunk-major bf16, o padded 11->16 with zeros
__global__ __launch_bounds__(256) void pack_dw_kernel(
    const float* __restrict__ dw, unsigned short* __restrict__ dwp)
{
    int e = blockIdx.x * 256 + threadIdx.x;    // 64*16*8 = 8192 halves
    int jb = e >> 7;
    int o = (e >> 3) & 15;
    int j = e & 7;
    float val = (o < OUTD) ? dw[o * CC + jb * 8 + j] : 0.f;
    dwp[e] = f2bf(val);
}

// GEMM: out[n][co] = act( A-window . W + bias ), all activations bf16.
// 128n x 128co tile, BK=128 ci-block (4 staging phases), 16x16x32 MFMA 4x4/wave.
// LDS: TWO slabs of pitch 64 halves (128 B) -- chunk bit3 selects slab, low 3
// bits XOR-swizzled by row&7 within slab. 128-B pitch = measured-zero-conflict
// geometry (R4/R5: 0 conflicts; 256-B pitch R6/R8: 4/read).
// B fragments direct from global (k-major WpT). 1-step software pipeline.
// XCD swizzle: 4 co-blocks of an n-window land on one XCD -> L2 fetches A once.
// HAS_RES: v = relu(relu(acc+b) + res_bf16); in-place-safe (lane-owned elems).
#define SLAB (136 * 64)
template <bool HAS_RES>
__global__ __launch_bounds__(256, 4) void conv_gemm(
    const unsigned short* __restrict__ Ain, const unsigned short* __restrict__ WpT,
    const float* __restrict__ bias, const unsigned short* __restrict__ resB,
    unsigned short* __restrict__ OutB, int d)
{
    __shared__ unsigned short sA[2 * SLAB];   // rows rbase-8..rbase+127, 2 x 64 halves

    const int tid = threadIdx.x;
    const int wave = tid >> 6, lane = tid & 63;

    const int bid = blockIdx.x;               // 0..1023
    const int xcd = bid & 7;
    const int local = bid >> 3;               // 0..127
    const int cb = local >> 5;                // 0..3
    const int nb = xcd + 8 * (local & 31);    // 0..255
    const int co0 = cb * 128;
    const int n0 = nb * 128;

    const int rbase = (n0 >> 10) * LROWS + LPAD + (n0 & (LL - 1));
    const int wm = (wave >> 1) * 64;           // wave n-stripe
    const int wn = (wave & 1) * 64;            // wave co-stripe
    const int lm = lane & 15, quad = lane >> 4;

    // staging lane decomposition: 8 rows x 8 chunks of 16B per llds16 (1 KB)
    const int r8 = lane >> 3;                  // row within 8-row segment
    const int c8 = lane & 7;                   // chunk position within slab

    f32x4 acc[4][4];
#pragma unroll
    for (int i = 0; i < 4; ++i)
#pragma unroll
        for (int j = 0; j < 4; ++j) acc[i][j] = (f32x4){0.f, 0.f, 0.f, 0.f};

    for (int it = 0; it < 4; ++it) {
        const int ci0 = it * 128;

        // stage A: 34 calls = 17 row-segments x 2 slabs; seg*8 % 8 == 0 so the
        // swizzle key for a lane's row is just r8.
        for (int sc = wave; sc < 34; sc += 4) {
            int seg = sc >> 1, slab = sc & 1;
            int cg = slab * 8 + (c8 ^ r8);                     // global 16B chunk
            const unsigned short* gA =
                Ain + (size_t)(rbase - 8 + seg * 8 + r8) * CC + ci0 + cg * 8;
            llds16(gA, sA + slab * SLAB + (seg * 8) * 64);     // lane*16B appended by HW
        }
        __syncthreads();

        // step s = t*4 + ks: t = tap (0 current, 1 past), ks = K=32 slice
        auto loadA = [&](int s, bf16x8* af) {
            const int t = s >> 2, ks = s & 3;
            const int shift = t ? d : 0;
            const int rowoff = 8 - shift + wm;
            const int key = (8 - shift + lm) & 7;              // row&7 of read row
            const int c = ks * 4 + quad;                       // 16B chunk 0..15
            const unsigned short* base = sA + (c >> 3) * SLAB + ((c & 7) ^ key) * 8;
#pragma unroll
            for (int mt = 0; mt < 4; ++mt)
                af[mt] = *(const bf16x8*)&base[(rowoff + mt * 16 + lm) * 64];
        };
        auto loadB = [&](int s, bf16x8* bf) {
            const int t = s >> 2, ks = s & 3;
            const int jb = t * 64 + it * 16 + ks * 4 + quad;   // global k-chunk
            const unsigned short* bbase = WpT + ((size_t)jb * 512 + co0 + wn + lm) * 8;
#pragma unroll
            for (int nt = 0; nt < 4; ++nt)
                bf[nt] = *(const bf16x8*)(bbase + (size_t)nt * 16 * 8);
        };

        bf16x8 afc[4], bfc[4], afn[4], bfn[4];
        loadA(0, afc);
        loadB(0, bfc);
#pragma unroll
        for (int s = 0; s < 8; ++s) {
            if (s < 7) { loadA(s + 1, afn); loadB(s + 1, bfn); }
#pragma unroll
            for (int mt = 0; mt < 4; ++mt)
#pragma unroll
                for (int nt = 0; nt < 4; ++nt)
                    acc[mt][nt] = __builtin_amdgcn_mfma_f32_16x16x32_bf16(
                        afc[mt], bfc[nt], acc[mt][nt], 0, 0, 0);
            if (s < 7) {
#pragma unroll
                for (int q2 = 0; q2 < 4; ++q2) { afc[q2] = afn[q2]; bfc[q2] = bfn[q2]; }
            }
        }
        __syncthreads();
    }

    // epilogue: C/D layout col(co)=lane&15, row(n)=quad*4+reg
    float bv[4];
#pragma unroll
    for (int nt = 0; nt < 4; ++nt) bv[nt] = bias[co0 + wn + nt * 16 + lm];

#pragma unroll
    for (int mt = 0; mt < 4; ++mt) {
        int prow0 = rbase + wm + mt * 16 + quad * 4;
#pragma unroll
        for (int nt = 0; nt < 4; ++nt) {
            int co = co0 + wn + nt * 16 + lm;
#pragma unroll
            for (int r = 0; r < 4; ++r) {
                size_t off = (size_t)(prow0 + r) * CC + co;
                float v = acc[mt][nt][r] + bv[nt];
                v = fmaxf(v, 0.f);
                if (HAS_RES) {
                    v += bf2f(resB[off]);
                    v = fmaxf(v, 0.f);
                }
                OutB[off] = f2bf(v);
            }
        }
    }
}

// decode as per-wave MFMA mini-GEMM: M=16 n, N=16 o (11 real), K=512.
// A-frag: lane(lm,quad) holds H[n0+lm][ks*32+quad*8 .. +8]
// B-frag from dwp (k-chunk-major, 16 KB, L1-resident).
// C/D: col=o=lane&15, row(n within 16)=quad*4+reg.
__global__ __launch_bounds__(256) void decode_kernel(
    const unsigned short* __restrict__ H, const unsigned short* __restrict__ dwp,
    const float* __restrict__ db, const int* __restrict__ mask,
    float* __restrict__ out)
{
    const int wave = threadIdx.x >> 6, lane = threadIdx.x & 63;
    const int lm = lane & 15, quad = lane >> 4;
    const int n0 = blockIdx.x * 64 + wave * 16;    // 64-aligned: no seq crossing
    const int prow = ((n0 + lm) >> 10) * LROWS + LPAD + ((n0 + lm) & (LL - 1));

    f32x4 acc = (f32x4){0.f, 0.f, 0.f, 0.f};
#pragma unroll
    for (int ks = 0; ks < 16; ++ks) {
        bf16x8 af = *(const bf16x8*)&H[(size_t)prow * CC + ks * 32 + quad * 8];
        bf16x8 bf = *(const bf16x8*)&dwp[((size_t)(ks * 4 + quad) * 16 + lm) * 8];
        acc = __builtin_amdgcn_mfma_f32_16x16x32_bf16(af, bf, acc, 0, 0, 0);
    }

    if (lm < OUTD) {
        float bo = db[lm];
#pragma unroll
        for (int r = 0; r < 4; ++r) {
            int n = n0 + quad * 4 + r;
            float v = (mask[n] != 0) ? (acc[r] + bo) : 0.f;
            out[(size_t)n * OUTD + lm] = v;
        }
    }
}

extern "C" void kernel_launch(void* const* d_in, const int* in_sizes, int n_in,
                              void* d_out, int out_size, void* d_ws, size_t ws_size,
                              hipStream_t stream)
{
    const int* x = (const int*)d_in[0];
    const int* mask = (const int*)d_in[1];   // jnp bool_ staged as int32
    const float* emb = (const float*)d_in[2];
    const float* w1 = (const float*)d_in[3];
    const float* b1 = (const float*)d_in[4];
    const float* w2 = (const float*)d_in[5];
    const float* b2 = (const float*)d_in[6];
    const float* dw = (const float*)d_in[7];
    const float* db = (const float*)d_in[8];
    float* out = (float*)d_out;

    char* ws = (char*)d_ws;
    const size_t HBB = (size_t)BB * LROWS * CC * 2;       // 33.8 MB (padded bf16)
    unsigned short* Hb0 = (unsigned short*)ws;
    unsigned short* Hb1 = (unsigned short*)(ws + HBB);
    unsigned short* WpT = (unsigned short*)(ws + 2 * HBB); // k-major bf16 weights, 8 MB
    unsigned short* dwp = (unsigned short*)(ws + 2 * HBB + (size_t)NLEVS * 2 * CC * 1024 * 2);

    zero_pad_kernel<<<128, 256, 0, stream>>>(Hb0, Hb1);
    embed_kernel<<<(NN * 64) / 256, 256, 0, stream>>>(x, emb, Hb0);
    pack_w_kernel<<<(NLEVS * 2 * CC * 1024) / 256, 256, 0, stream>>>(w1, w2, WpT);
    pack_dw_kernel<<<32, 256, 0, stream>>>(dw, dwp);

    const int grid = (CC / 128) * (NN / 128);   // 4 * 256 = 1024 blocks = 4/CU
    for (int i = 0; i < NLEVS; ++i) {
        int d = 1 << i;
        const unsigned short* W1 = WpT + (size_t)(i * 2 + 0) * CC * 1024;
        const unsigned short* W2 = WpT + (size_t)(i * 2 + 1) * CC * 1024;
        // conv1: A=Hb0 -> Hb1
        conv_gemm<false><<<grid, 256, 0, stream>>>(Hb0, W1, b1 + i * CC, nullptr, Hb1, d);
        // conv2: A=Hb1, res=Hb0 (bf16), out=Hb0 (in place, lane-owned)
        conv_gemm<true><<<grid, 256, 0, stream>>>(Hb1, W2, b2 + i * CC, Hb0, Hb0, d);
    }
    decode_kernel<<<NN / 64, 256, 0, stream>>>(Hb0, dwp, db, mask, out);
}

// Round 10
// 392.150 us; speedup vs baseline: 1.1382x; 1.0093x over previous
//
#include <hip/hip_runtime.h>
#include <stdint.h>

#define BB 32
#define LL 1024
#define CC 512
#define NN (BB * LL)      // 32768 positions
#define NLEVS 4
#define OUTD 11
#define LPAD 8            // zero pad rows per sequence (>= max dilation)
#define LROWS (LL + LPAD) // 1032 padded rows per sequence

typedef __attribute__((ext_vector_type(8))) short bf16x8;
typedef __attribute__((ext_vector_type(4))) float f32x4;

static __device__ __forceinline__ unsigned short f2bf(float f) {
    union { float f; uint32_t u; } v; v.f = f;
    uint32_t u = v.u;
    uint32_t r = (u + 0x7fffu + ((u >> 16) & 1u)) >> 16;  // RNE
    return (unsigned short)r;
}
static __device__ __forceinline__ float bf2f(unsigned short h) {
    union { uint32_t u; float f; } v; v.u = ((uint32_t)h) << 16;
    return v.f;
}

// async 16B global -> LDS (wave-uniform LDS base + lane*16)
static __device__ __forceinline__ void llds16(const unsigned short* g, unsigned short* l) {
    __builtin_amdgcn_global_load_lds(
        (const __attribute__((address_space(1))) unsigned int*)g,
        (__attribute__((address_space(3))) unsigned int*)l, 16, 0, 0);
}

// Fused prep: pack_w | embed | zero_pad | pack_dw, selected by block range.
// pack_w blocks:  [0, 16384)          4.2M elements
// embed blocks:   [16384, 24576)      2.1M x (8 halves)
// zero blocks:    [24576, 24704)      pad rows of Hb0/Hb1
// dwp blocks:     [24704, 24736)      decoder weights k-major, o padded to 16
__global__ __launch_bounds__(256) void prep_kernel(
    const int* __restrict__ x, const float* __restrict__ emb,
    const float* __restrict__ w1, const float* __restrict__ w2,
    const float* __restrict__ dw,
    unsigned short* __restrict__ Hb0, unsigned short* __restrict__ Hb1,
    unsigned short* __restrict__ WpT, unsigned short* __restrict__ dwp)
{
    int b = blockIdx.x;
    if (b < 16384) {
        // WpT[cv][j][co][h]; kidx=j*8+h; kidx<512 -> tap k=1 (current), else k=0
        int e = b * 256 + threadIdx.x;
        int cv = e >> 19;
        int r = e & 524287;
        int j = r >> 12;
        int co = (r >> 3) & 511;
        int h = r & 7;
        int kidx = j * 8 + h;
        int k = (kidx < 512) ? 1 : 0;
        int ci = kidx & 511;
        int lvl = cv >> 1;
        const float* w = (cv & 1) ? w2 : w1;
        WpT[e] = f2bf(w[(((size_t)(lvl * 512 + co) * 512) + ci) * 2 + k]);
    } else if (b < 24576) {
        int t = (b - 16384) * 256 + threadIdx.x;
        int n = t >> 6;
        int c8 = (t & 63) * 8;
        int idx = x[n];
        const float* src = emb + (size_t)idx * CC + c8;
        float4 v0 = *(const float4*)src;
        float4 v1 = *(const float4*)(src + 4);
        ushort4 a, bb;
        a.x = f2bf(v0.x); a.y = f2bf(v0.y); a.z = f2bf(v0.z); a.w = f2bf(v0.w);
        bb.x = f2bf(v1.x); bb.y = f2bf(v1.y); bb.z = f2bf(v1.z); bb.w = f2bf(v1.w);
        int prow = (n >> 10) * LROWS + LPAD + (n & (LL - 1));
        unsigned short* dst = Hb0 + (size_t)prow * CC + c8;
        *(ushort4*)dst = a;
        *(ushort4*)(dst + 4) = bb;
    } else if (b < 24704) {
        int t = (b - 24576) * 256 + threadIdx.x;   // 32768 uint4 stores
        unsigned short* base = (t >> 14) ? Hb1 : Hb0;
        int rem = t & 16383;
        int p = rem >> 9;
        int q = rem & 511;
        size_t off = (size_t)p * (LROWS * CC) + (size_t)q * 8;
        *(uint4*)(base + off) = (uint4){0u, 0u, 0u, 0u};
    } else {
        int e = (b - 24704) * 256 + threadIdx.x;   // 8192 halves
        int jb = e >> 7;
        int o = (e >> 3) & 15;
        int j = e & 7;
        dwp[e] = f2bf((o < OUTD) ? dw[o * CC + jb * 8 + j] : 0.f);
    }
}

// GEMM: out[n][co] = act( A-window . W + bias ), all activations bf16.
// 128n x 128co tile, BK=64 per LDS buffer, DOUBLE-BUFFERED async A staging:
// stage(it+1 -> other buf) issued before compute(it) so the barrier's vmcnt(0)
// drains loads that were in flight for the whole compute phase.
// 16x16x32 MFMA 4x4/wave; LDS slab pitch 64 halves (128 B), chunks 0..7 XOR-
// swizzled by row&7 = the measured-zero-conflict geometry (R3/R5/R9).
// B fragments direct from global (k-major WpT). 1-step register pipeline.
// XCD swizzle: 4 co-blocks of an n-window land on one XCD -> L2 fetches A once.
// HAS_RES: v = relu(relu(acc+b) + res_bf16); in-place-safe (lane-owned elems).
#define BUFH (17 * 512)   // 136 rows x 64 halves = 8704 halves = 17408 B
template <bool HAS_RES>
__global__ __launch_bounds__(256, 4) void conv_gemm(
    const unsigned short* __restrict__ Ain, const unsigned short* __restrict__ WpT,
    const float* __restrict__ bias, const unsigned short* __restrict__ resB,
    unsigned short* __restrict__ OutB, int d)
{
    __shared__ unsigned short sA[2 * BUFH];

    const int tid = threadIdx.x;
    const int wave = tid >> 6, lane = tid & 63;

    const int bid = blockIdx.x;               // 0..1023
    const int xcd = bid & 7;
    const int local = bid >> 3;               // 0..127
    const int cb = local >> 5;                // 0..3
    const int nb = xcd + 8 * (local & 31);    // 0..255
    const int co0 = cb * 128;
    const int n0 = nb * 128;

    const int rbase = (n0 >> 10) * LROWS + LPAD + (n0 & (LL - 1));
    const int wm = (wave >> 1) * 64;           // wave n-stripe
    const int wn = (wave & 1) * 64;            // wave co-stripe
    const int lm = lane & 15, quad = lane >> 4;

    // staging lane decomposition: 8 rows x 8 chunks of 16B per llds16 (1 KB)
    const int r8 = lane >> 3;
    const int c8 = lane & 7;

    f32x4 acc[4][4];
#pragma unroll
    for (int i = 0; i < 4; ++i)
#pragma unroll
        for (int j = 0; j < 4; ++j) acc[i][j] = (f32x4){0.f, 0.f, 0.f, 0.f};

    // stage ci-block `it` (64 halves of 136 rows) into buffer `buf`
    auto stage = [&](int it, int buf) {
        const int ci0 = it * 64;
        const unsigned short* gA =
            Ain + (size_t)(rbase - 8 + r8) * CC + ci0 + (c8 ^ r8) * 8;
        unsigned short* lbase = sA + buf * BUFH;
        for (int seg = wave; seg < 17; seg += 4)
            llds16(gA + (size_t)seg * 8 * CC, lbase + seg * 512);
    };

    stage(0, 0);
    __syncthreads();

    for (int it = 0; it < 8; ++it) {
        if (it < 7) stage(it + 1, (it + 1) & 1);
        const unsigned short* buf = sA + (it & 1) * BUFH;
        const int jb0 = it * 8;                     // global k-chunk base (per tap)

        // step s = t*2 + ks: t = tap (0 current, 1 past), ks = K=32 slice
        auto loadA = [&](int s, bf16x8* af) {
            const int t = s >> 1, ks = s & 1;
            const int shift = t ? d : 0;
            const int rowoff = 8 - shift + wm;
            const int key = (8 - shift + lm) & 7;
            const int cpos = ((ks * 4 + quad) ^ key);
#pragma unroll
            for (int mt = 0; mt < 4; ++mt)
                af[mt] = *(const bf16x8*)&buf[(rowoff + mt * 16 + lm) * 64 + cpos * 8];
        };
        auto loadB = [&](int s, bf16x8* bf) {
            const int t = s >> 1, ks = s & 1;
            const int jb = t * 64 + jb0 + ks * 4 + quad;
            const unsigned short* bbase = WpT + ((size_t)jb * 512 + co0 + wn + lm) * 8;
#pragma unroll
            for (int nt = 0; nt < 4; ++nt)
                bf[nt] = *(const bf16x8*)(bbase + (size_t)nt * 16 * 8);
        };

        bf16x8 afc[4], bfc[4], afn[4], bfn[4];
        loadA(0, afc);
        loadB(0, bfc);
#pragma unroll
        for (int s = 0; s < 4; ++s) {
            if (s < 3) { loadA(s + 1, afn); loadB(s + 1, bfn); }
#pragma unroll
            for (int mt = 0; mt < 4; ++mt)
#pragma unroll
                for (int nt = 0; nt < 4; ++nt)
                    acc[mt][nt] = __builtin_amdgcn_mfma_f32_16x16x32_bf16(
                        afc[mt], bfc[nt], acc[mt][nt], 0, 0, 0);
            if (s < 3) {
#pragma unroll
                for (int q2 = 0; q2 < 4; ++q2) { afc[q2] = afn[q2]; bfc[q2] = bfn[q2]; }
            }
        }
        __syncthreads();   // drains stage(it+1) loads (in flight during compute)
    }

    // epilogue: C/D layout col(co)=lane&15, row(n)=quad*4+reg
    float bv[4];
#pragma unroll
    for (int nt = 0; nt < 4; ++nt) bv[nt] = bias[co0 + wn + nt * 16 + lm];

#pragma unroll
    for (int mt = 0; mt < 4; ++mt) {
        int prow0 = rbase + wm + mt * 16 + quad * 4;
#pragma unroll
        for (int nt = 0; nt < 4; ++nt) {
            int co = co0 + wn + nt * 16 + lm;
#pragma unroll
            for (int r = 0; r < 4; ++r) {
                size_t off = (size_t)(prow0 + r) * CC + co;
                float v = acc[mt][nt][r] + bv[nt];
                v = fmaxf(v, 0.f);
                if (HAS_RES) {
                    v += bf2f(resB[off]);
                    v = fmaxf(v, 0.f);
                }
                OutB[off] = f2bf(v);
            }
        }
    }
}

// decode as per-wave MFMA mini-GEMM: M=16 n, N=16 o (11 real), K=512.
__global__ __launch_bounds__(256) void decode_kernel(
    const unsigned short* __restrict__ H, const unsigned short* __restrict__ dwp,
    const float* __restrict__ db, const int* __restrict__ mask,
    float* __restrict__ out)
{
    const int wave = threadIdx.x >> 6, lane = threadIdx.x & 63;
    const int lm = lane & 15, quad = lane >> 4;
    const int n0 = blockIdx.x * 64 + wave * 16;    // 64-aligned: no seq crossing
    const int prow = ((n0 + lm) >> 10) * LROWS + LPAD + ((n0 + lm) & (LL - 1));

    f32x4 acc = (f32x4){0.f, 0.f, 0.f, 0.f};
#pragma unroll
    for (int ks = 0; ks < 16; ++ks) {
        bf16x8 af = *(const bf16x8*)&H[(size_t)prow * CC + ks * 32 + quad * 8];
        bf16x8 bf = *(const bf16x8*)&dwp[((size_t)(ks * 4 + quad) * 16 + lm) * 8];
        acc = __builtin_amdgcn_mfma_f32_16x16x32_bf16(af, bf, acc, 0, 0, 0);
    }

    if (lm < OUTD) {
        float bo = db[lm];
#pragma unroll
        for (int r = 0; r < 4; ++r) {
            int n = n0 + quad * 4 + r;
            float v = (mask[n] != 0) ? (acc[r] + bo) : 0.f;
            out[(size_t)n * OUTD + lm] = v;
        }
    }
}

extern "C" void kernel_launch(void* const* d_in, const int* in_sizes, int n_in,
                              void* d_out, int out_size, void* d_ws, size_t ws_size,
                              hipStream_t stream)
{
    const int* x = (const int*)d_in[0];
    const int* mask = (const int*)d_in[1];   // jnp bool_ staged as int32
    const float* emb = (const float*)d_in[2];
    const float* w1 = (const float*)d_in[3];
    const float* b1 = (const float*)d_in[4];
    const float* w2 = (const float*)d_in[5];
    const float* b2 = (const float*)d_in[6];
    const float* dw = (const float*)d_in[7];
    const float* db = (const float*)d_in[8];
    float* out = (float*)d_out;

    char* ws = (char*)d_ws;
    const size_t HBB = (size_t)BB * LROWS * CC * 2;       // 33.8 MB (padded bf16)
    unsigned short* Hb0 = (unsigned short*)ws;
    unsigned short* Hb1 = (unsigned short*)(ws + HBB);
    unsigned short* WpT = (unsigned short*)(ws + 2 * HBB); // k-major bf16 weights, 8 MB
    unsigned short* dwp = (unsigned short*)(ws + 2 * HBB + (size_t)NLEVS * 2 * CC * 1024 * 2);

    prep_kernel<<<24736, 256, 0, stream>>>(x, emb, w1, w2, dw, Hb0, Hb1, WpT, dwp);

    const int grid = (CC / 128) * (NN / 128);   // 4 * 256 = 1024 blocks = 4/CU
    for (int i = 0; i < NLEVS; ++i) {
        int d = 1 << i;
        const unsigned short* W1 = WpT + (size_t)(i * 2 + 0) * CC * 1024;
        const unsigned short* W2 = WpT + (size_t)(i * 2 + 1) * CC * 1024;
        // conv1: A=Hb0 -> Hb1
        conv_gemm<false><<<grid, 256, 0, stream>>>(Hb0, W1, b1 + i * CC, nullptr, Hb1, d);
        // conv2: A=Hb1, res=Hb0 (bf16), out=Hb0 (in place, lane-owned)
        conv_gemm<true><<<grid, 256, 0, stream>>>(Hb1, W2, b2 + i * CC, Hb0, Hb0, d);
    }
    decode_kernel<<<NN / 64, 256, 0, stream>>>(Hb0, dwp, db, mask, out);
}

// Round 11
// 379.791 us; speedup vs baseline: 1.1753x; 1.0325x over previous
//
#include <hip/hip_runtime.h>
#include <stdint.h>

#define BB 32
#define LL 1024
#define CC 512
#define NN (BB * LL)      // 32768 positions
#define NLEVS 4
#define OUTD 11
#define LPAD 8            // zero pad rows per sequence (>= max dilation)
#define LROWS (LL + LPAD) // 1032 padded rows per sequence

typedef __attribute__((ext_vector_type(8))) short bf16x8;
typedef __attribute__((ext_vector_type(4))) float f32x4;

static __device__ __forceinline__ unsigned short f2bf(float f) {
    union { float f; uint32_t u; } v; v.f = f;
    uint32_t u = v.u;
    uint32_t r = (u + 0x7fffu + ((u >> 16) & 1u)) >> 16;  // RNE
    return (unsigned short)r;
}
static __device__ __forceinline__ float bf2f(unsigned short h) {
    union { uint32_t u; float f; } v; v.u = ((uint32_t)h) << 16;
    return v.f;
}

// async 16B global -> LDS (wave-uniform LDS base + lane*16)
static __device__ __forceinline__ void llds16(const unsigned short* g, unsigned short* l) {
    __builtin_amdgcn_global_load_lds(
        (const __attribute__((address_space(1))) unsigned int*)g,
        (__attribute__((address_space(3))) unsigned int*)l, 16, 0, 0);
}

// Fused prep: pack_w | embed | zero_pad | pack_dw, selected by block range.
__global__ __launch_bounds__(256) void prep_kernel(
    const int* __restrict__ x, const float* __restrict__ emb,
    const float* __restrict__ w1, const float* __restrict__ w2,
    const float* __restrict__ dw,
    unsigned short* __restrict__ Hb0, unsigned short* __restrict__ Hb1,
    unsigned short* __restrict__ WpT, unsigned short* __restrict__ dwp)
{
    int b = blockIdx.x;
    if (b < 16384) {
        // WpT[cv][j][co][h]; kidx=j*8+h; kidx<512 -> tap k=1 (current), else k=0
        int e = b * 256 + threadIdx.x;
        int cv = e >> 19;
        int r = e & 524287;
        int j = r >> 12;
        int co = (r >> 3) & 511;
        int h = r & 7;
        int kidx = j * 8 + h;
        int k = (kidx < 512) ? 1 : 0;
        int ci = kidx & 511;
        int lvl = cv >> 1;
        const float* w = (cv & 1) ? w2 : w1;
        WpT[e] = f2bf(w[(((size_t)(lvl * 512 + co) * 512) + ci) * 2 + k]);
    } else if (b < 24576) {
        int t = (b - 16384) * 256 + threadIdx.x;
        int n = t >> 6;
        int c8 = (t & 63) * 8;
        int idx = x[n];
        const float* src = emb + (size_t)idx * CC + c8;
        float4 v0 = *(const float4*)src;
        float4 v1 = *(const float4*)(src + 4);
        ushort4 a, bb;
        a.x = f2bf(v0.x); a.y = f2bf(v0.y); a.z = f2bf(v0.z); a.w = f2bf(v0.w);
        bb.x = f2bf(v1.x); bb.y = f2bf(v1.y); bb.z = f2bf(v1.z); bb.w = f2bf(v1.w);
        int prow = (n >> 10) * LROWS + LPAD + (n & (LL - 1));
        unsigned short* dst = Hb0 + (size_t)prow * CC + c8;
        *(ushort4*)dst = a;
        *(ushort4*)(dst + 4) = bb;
    } else if (b < 24704) {
        int t = (b - 24576) * 256 + threadIdx.x;   // 32768 uint4 stores
        unsigned short* base = (t >> 14) ? Hb1 : Hb0;
        int rem = t & 16383;
        int p = rem >> 9;
        int q = rem & 511;
        size_t off = (size_t)p * (LROWS * CC) + (size_t)q * 8;
        *(uint4*)(base + off) = (uint4){0u, 0u, 0u, 0u};
    } else {
        int e = (b - 24704) * 256 + threadIdx.x;   // 8192 halves
        int jb = e >> 7;
        int o = (e >> 3) & 15;
        int j = e & 7;
        dwp[e] = f2bf((o < OUTD) ? dw[o * CC + jb * 8 + j] : 0.f);
    }
}

// GEMM: out[n][co] = act( A-window . W + bias ), all activations bf16.
// 128n x 128co tile, BK=64/buffer, 2 LDS slots. BARRIER-FREE K-loop:
// per wave/it: spin done[it-1]==4 -> issue A loads for it+1 ->
// s_waitcnt vmcnt(4|5) (drains it's loads only; it+1's stay in flight through
// the whole compute phase) -> ready[it]+=1 -> spin ready[it]==4 -> compute(it)
// -> done[it]+=1. No __syncthreads in the loop => no forced vmcnt(0) drain
// (the m97-plateau stall). 16x16x32 MFMA 4x4/wave; 128-B-pitch XOR-swizzled
// LDS (measured-zero-conflict geometry). B direct from global (k-major WpT).
// XCD swizzle: 4 co-blocks of an n-window land on one XCD.
// HAS_RES: v = relu(relu(acc+b) + res_bf16); in-place-safe (lane-owned elems).
#define BUFH (17 * 512)   // 136 rows x 64 halves = 17408 B per buffer
template <bool HAS_RES>
__global__ __launch_bounds__(256, 4) void conv_gemm(
    const unsigned short* __restrict__ Ain, const unsigned short* __restrict__ WpT,
    const float* __restrict__ bias, const unsigned short* __restrict__ resB,
    unsigned short* __restrict__ OutB, int d)
{
    __shared__ unsigned short sA[2 * BUFH];
    __shared__ int s_ready[8];
    __shared__ int s_done[8];

    const int tid = threadIdx.x;
    const int wave = tid >> 6, lane = tid & 63;

    const int bid = blockIdx.x;               // 0..1023
    const int xcd = bid & 7;
    const int local = bid >> 3;               // 0..127
    const int cb = local >> 5;                // 0..3
    const int nb = xcd + 8 * (local & 31);    // 0..255
    const int co0 = cb * 128;
    const int n0 = nb * 128;

    const int rbase = (n0 >> 10) * LROWS + LPAD + (n0 & (LL - 1));
    const int wm = (wave >> 1) * 64;           // wave n-stripe
    const int wn = (wave & 1) * 64;            // wave co-stripe
    const int lm = lane & 15, quad = lane >> 4;

    // staging lane decomposition: 8 rows x 8 chunks of 16B per llds16 (1 KB)
    const int r8 = lane >> 3;
    const int c8 = lane & 7;

    if (tid < 8) { s_ready[tid] = 0; s_done[tid] = 0; }
    __syncthreads();

    f32x4 acc[4][4];
#pragma unroll
    for (int i = 0; i < 4; ++i)
#pragma unroll
        for (int j = 0; j < 4; ++j) acc[i][j] = (f32x4){0.f, 0.f, 0.f, 0.f};

    // issue this wave's segments of ci-block `it` into slot it&1
    // wave0: segs 0,4,8,12,16 (5 loads); waves1-3: 4 loads
    auto issue = [&](int it) {
        const unsigned short* gA =
            Ain + (size_t)(rbase - 8 + r8) * CC + it * 64 + (c8 ^ r8) * 8;
        unsigned short* lbase = sA + (it & 1) * BUFH;
        for (int seg = wave; seg < 17; seg += 4)
            llds16(gA + (size_t)seg * 8 * CC, lbase + seg * 512);
    };
    auto spin4 = [&](int* p) {
        volatile int* vp = (volatile int*)p;
        while (*vp < 4) __builtin_amdgcn_s_sleep(1);
    };

    issue(0);

    for (int it = 0; it < 8; ++it) {
        if (it < 7) {
            if (it >= 1) spin4(&s_done[it - 1]);     // slot (it+1)&1 free?
            issue(it + 1);
            // drain it's loads only; leave it+1's in flight (wave0 issued 5)
            if (wave == 0) __builtin_amdgcn_s_waitcnt(0xF75);  // vmcnt(5)
            else           __builtin_amdgcn_s_waitcnt(0xF74);  // vmcnt(4)
        } else {
            __builtin_amdgcn_s_waitcnt(0xF70);                 // vmcnt(0)
        }
        __asm__ volatile("" ::: "memory");
        if (lane == 0) atomicAdd(&s_ready[it], 1);
        spin4(&s_ready[it]);
        __asm__ volatile("" ::: "memory");

        const unsigned short* buf = sA + (it & 1) * BUFH;
        const int jb0 = it * 8;

        // step s = t*2 + ks: t = tap (0 current, 1 past), ks = K=32 slice
        auto loadA = [&](int s, bf16x8* af) {
            const int t = s >> 1, ks = s & 1;
            const int shift = t ? d : 0;
            const int rowoff = 8 - shift + wm;
            const int key = (8 - shift + lm) & 7;
            const int cpos = ((ks * 4 + quad) ^ key);
#pragma unroll
            for (int mt = 0; mt < 4; ++mt)
                af[mt] = *(const bf16x8*)&buf[(rowoff + mt * 16 + lm) * 64 + cpos * 8];
        };
        auto loadB = [&](int s, bf16x8* bf) {
            const int t = s >> 1, ks = s & 1;
            const int jb = t * 64 + jb0 + ks * 4 + quad;
            const unsigned short* bbase = WpT + ((size_t)jb * 512 + co0 + wn + lm) * 8;
#pragma unroll
            for (int nt = 0; nt < 4; ++nt)
                bf[nt] = *(const bf16x8*)(bbase + (size_t)nt * 16 * 8);
        };

        bf16x8 afc[4], bfc[4], afn[4], bfn[4];
        loadA(0, afc);
        loadB(0, bfc);
#pragma unroll
        for (int s = 0; s < 4; ++s) {
            if (s < 3) { loadA(s + 1, afn); loadB(s + 1, bfn); }
#pragma unroll
            for (int mt = 0; mt < 4; ++mt)
#pragma unroll
                for (int nt = 0; nt < 4; ++nt)
                    acc[mt][nt] = __builtin_amdgcn_mfma_f32_16x16x32_bf16(
                        afc[mt], bfc[nt], acc[mt][nt], 0, 0, 0);
            if (s < 3) {
#pragma unroll
                for (int q2 = 0; q2 < 4; ++q2) { afc[q2] = afn[q2]; bfc[q2] = bfn[q2]; }
            }
        }

        __asm__ volatile("" ::: "memory");
        if (lane == 0) atomicAdd(&s_done[it], 1);
    }

    // epilogue: C/D layout col(co)=lane&15, row(n)=quad*4+reg
    float bv[4];
#pragma unroll
    for (int nt = 0; nt < 4; ++nt) bv[nt] = bias[co0 + wn + nt * 16 + lm];

#pragma unroll
    for (int mt = 0; mt < 4; ++mt) {
        int prow0 = rbase + wm + mt * 16 + quad * 4;
#pragma unroll
        for (int nt = 0; nt < 4; ++nt) {
            int co = co0 + wn + nt * 16 + lm;
#pragma unroll
            for (int r = 0; r < 4; ++r) {
                size_t off = (size_t)(prow0 + r) * CC + co;
                float v = acc[mt][nt][r] + bv[nt];
                v = fmaxf(v, 0.f);
                if (HAS_RES) {
                    v += bf2f(resB[off]);
                    v = fmaxf(v, 0.f);
                }
                OutB[off] = f2bf(v);
            }
        }
    }
}

// decode as per-wave MFMA mini-GEMM: M=16 n, N=16 o (11 real), K=512.
__global__ __launch_bounds__(256) void decode_kernel(
    const unsigned short* __restrict__ H, const unsigned short* __restrict__ dwp,
    const float* __restrict__ db, const int* __restrict__ mask,
    float* __restrict__ out)
{
    const int wave = threadIdx.x >> 6, lane = threadIdx.x & 63;
    const int lm = lane & 15, quad = lane >> 4;
    const int n0 = blockIdx.x * 64 + wave * 16;    // 64-aligned: no seq crossing
    const int prow = ((n0 + lm) >> 10) * LROWS + LPAD + ((n0 + lm) & (LL - 1));

    f32x4 acc = (f32x4){0.f, 0.f, 0.f, 0.f};
#pragma unroll
    for (int ks = 0; ks < 16; ++ks) {
        bf16x8 af = *(const bf16x8*)&H[(size_t)prow * CC + ks * 32 + quad * 8];
        bf16x8 bf = *(const bf16x8*)&dwp[((size_t)(ks * 4 + quad) * 16 + lm) * 8];
        acc = __builtin_amdgcn_mfma_f32_16x16x32_bf16(af, bf, acc, 0, 0, 0);
    }

    if (lm < OUTD) {
        float bo = db[lm];
#pragma unroll
        for (int r = 0; r < 4; ++r) {
            int n = n0 + quad * 4 + r;
            float v = (mask[n] != 0) ? (acc[r] + bo) : 0.f;
            out[(size_t)n * OUTD + lm] = v;
        }
    }
}

extern "C" void kernel_launch(void* const* d_in, const int* in_sizes, int n_in,
                              void* d_out, int out_size, void* d_ws, size_t ws_size,
                              hipStream_t stream)
{
    const int* x = (const int*)d_in[0];
    const int* mask = (const int*)d_in[1];   // jnp bool_ staged as int32
    const float* emb = (const float*)d_in[2];
    const float* w1 = (const float*)d_in[3];
    const float* b1 = (const float*)d_in[4];
    const float* w2 = (const float*)d_in[5];
    const float* b2 = (const float*)d_in[6];
    const float* dw = (const float*)d_in[7];
    const float* db = (const float*)d_in[8];
    float* out = (float*)d_out;

    char* ws = (char*)d_ws;
    const size_t HBB = (size_t)BB * LROWS * CC * 2;       // 33.8 MB (padded bf16)
    unsigned short* Hb0 = (unsigned short*)ws;
    unsigned short* Hb1 = (unsigned short*)(ws + HBB);
    unsigned short* WpT = (unsigned short*)(ws + 2 * HBB); // k-major bf16 weights, 8 MB
    unsigned short* dwp = (unsigned short*)(ws + 2 * HBB + (size_t)NLEVS * 2 * CC * 1024 * 2);

    prep_kernel<<<24736, 256, 0, stream>>>(x, emb, w1, w2, dw, Hb0, Hb1, WpT, dwp);

    const int grid = (CC / 128) * (NN / 128);   // 4 * 256 = 1024 blocks = 4/CU
    for (int i = 0; i < NLEVS; ++i) {
        int d = 1 << i;
        const unsigned short* W1 = WpT + (size_t)(i * 2 + 0) * CC * 1024;
        const unsigned short* W2 = WpT + (size_t)(i * 2 + 1) * CC * 1024;
        // conv1: A=Hb0 -> Hb1
        conv_gemm<false><<<grid, 256, 0, stream>>>(Hb0, W1, b1 + i * CC, nullptr, Hb1, d);
        // conv2: A=Hb1, res=Hb0 (bf16), out=Hb0 (in place, lane-owned)
        conv_gemm<true><<<grid, 256, 0, stream>>>(Hb1, W2, b2 + i * CC, Hb0, Hb0, d);
    }
    decode_kernel<<<NN / 64, 256, 0, stream>>>(Hb0, dwp, db, mask, out);
}